// Round 10
// baseline (11257.737 us; speedup 1.0000x reference)
//
#include <hip/hip_runtime.h>
#include <hip/hip_bf16.h>
#include <math.h>

typedef unsigned short u16;
typedef unsigned long long u64;
typedef __attribute__((ext_vector_type(8))) short short8;
typedef __attribute__((ext_vector_type(4))) float f32x4;

static __device__ __forceinline__ u16 f2b(float x) {
  __hip_bfloat16 h = __float2bfloat16(x);
  return *reinterpret_cast<u16*>(&h);
}
static __device__ __forceinline__ float b2f(u16 u) {
  unsigned int v = ((unsigned int)u) << 16;
  float f;
  __builtin_memcpy(&f, &v, 4);
  return f;
}

// agent-scope relaxed (coherence-point) store
static __device__ __forceinline__ void astf(float* p, float v) {
  __hip_atomic_store(p, v, __ATOMIC_RELAXED, __HIP_MEMORY_SCOPE_AGENT);
}

// ---------------- conversion kernels ----------------

__global__ void cvt_flat(const float* __restrict__ s, u16* __restrict__ d, long n) {
  long i = ((long)blockIdx.x * 256 + threadIdx.x) * 4;
  long stride = (long)gridDim.x * 1024;
  for (; i < n; i += stride) {
    float4 v = *(const float4*)(s + i);
    ushort4 o;
    o.x = f2b(v.x); o.y = f2b(v.y); o.z = f2b(v.z); o.w = f2b(v.w);
    *(ushort4*)(d + i) = o;
  }
}

__global__ void cvt_strided(const float* __restrict__ s, u16* __restrict__ d,
                            long total, int lshift, long sstride, long soff) {
  long i = (long)blockIdx.x * 256 + threadIdx.x;
  long step = (long)gridDim.x * 256;
  long mask = (1L << lshift) - 1;
  for (; i < total; i += step) {
    long r = i >> lshift;
    long c = i & mask;
    d[i] = f2b(s[r * sstride + soff + c]);
  }
}

__global__ void cvt_x(const float* __restrict__ gt, u16* __restrict__ d) {
  long idx = (long)blockIdx.x * 256 + threadIdx.x;
  if (idx >= 1024L * 512) return;
  long m = idx >> 9;
  int k = (int)(idx & 511);
  if (m < 992) {
    int tt = (int)(m >> 5), b = (int)(m & 31);
    d[idx] = f2b(gt[((long)b * 32 + tt) * 512 + k]);
  } else {
    d[idx] = 0;
  }
}

// h0 -> hstage[0] in the phase-A-coalesced permuted layout:
// idx(b,m) = b*1024 + ((m&63)>>2)*64 + (m>>6)*4 + (m&3)
__global__ void cvt_hperm(const float* __restrict__ h0, float* __restrict__ d) {
  int i = blockIdx.x * 256 + threadIdx.x;  // 32768
  if (i >= 32768) return;
  int b = i >> 10, m = i & 1023;
  d[b * 1024 + ((m & 63) >> 2) * 64 + (m >> 6) * 4 + (m & 3)] = h0[i];
}

// ---------------- generic MFMA GEMM: C = A(M,K) * B(N,K)^T ----------------
template<int EPI>
__global__ __launch_bounds__(256)
void gemm_bt(const u16* __restrict__ A, const u16* __restrict__ B,
             void* __restrict__ C0,
             const float* __restrict__ bias, const float* __restrict__ pw,
             int M, int N, int K) {
  __shared__ u16 As[4096];
  __shared__ u16 Bs[4096];
  const int tid = threadIdx.x;
  const int lane = tid & 63, wid = tid >> 6;

  int gx = gridDim.x, gy = gridDim.y;
  int orig = blockIdx.y * gx + blockIdx.x;
  int G = gx < 8 ? gx : 8;
  int ng = gx / G;
  int full = ng * G * gy;
  int ct, rt;
  if (orig < full) {
    int grp = orig / (G * gy), rem = orig % (G * gy);
    ct = grp * G + rem % G;
    rt = rem / G;
  } else {
    int Gt = gx - ng * G;
    int rem = orig - full;
    ct = ng * G + rem % Gt;
    rt = rem / Gt;
  }
  const long row0 = (long)rt * 128;
  const long col0 = (long)ct * 128;

  const int wm = (wid >> 1) * 64, wn = (wid & 1) * 64;
  const int fr = lane & 15, fq = lane >> 4;
  const int sr = wid * 16 + (lane >> 2);
  const int sc = (lane & 3) * 8;

  const u16* Ag0 = A + (row0 + sr) * (long)K + sc;
  const u16* Ag1 = Ag0 + 64 * (long)K;
  const u16* Bg0 = B + (col0 + sr) * (long)K + sc;
  const u16* Bg1 = Bg0 + 64 * (long)K;

  u16* AsW0 = &As[wid * 512];
  u16* AsW1 = &As[2048 + wid * 512];
  u16* BsW0 = &Bs[wid * 512];
  u16* BsW1 = &Bs[2048 + wid * 512];

  f32x4 acc[4][4];
#pragma unroll
  for (int i = 0; i < 4; ++i)
#pragma unroll
    for (int j = 0; j < 4; ++j) acc[i][j] = {0.f, 0.f, 0.f, 0.f};

  for (int k0 = 0; k0 < K; k0 += 32) {
    __builtin_amdgcn_global_load_lds((const __attribute__((address_space(1))) void*)(Ag0 + k0),
                                     (__attribute__((address_space(3))) void*)AsW0, 16, 0, 0);
    __builtin_amdgcn_global_load_lds((const __attribute__((address_space(1))) void*)(Ag1 + k0),
                                     (__attribute__((address_space(3))) void*)AsW1, 16, 0, 0);
    __builtin_amdgcn_global_load_lds((const __attribute__((address_space(1))) void*)(Bg0 + k0),
                                     (__attribute__((address_space(3))) void*)BsW0, 16, 0, 0);
    __builtin_amdgcn_global_load_lds((const __attribute__((address_space(1))) void*)(Bg1 + k0),
                                     (__attribute__((address_space(3))) void*)BsW1, 16, 0, 0);
    __syncthreads();
    short8 af[4], bfv[4];
#pragma unroll
    for (int i = 0; i < 4; ++i) af[i] = *(const short8*)&As[(wm + i * 16 + fr) * 32 + fq * 8];
#pragma unroll
    for (int i = 0; i < 4; ++i) bfv[i] = *(const short8*)&Bs[(wn + i * 16 + fr) * 32 + fq * 8];
#pragma unroll
    for (int i = 0; i < 4; ++i)
#pragma unroll
      for (int j = 0; j < 4; ++j)
        acc[i][j] = __builtin_amdgcn_mfma_f32_16x16x32_bf16(af[i], bfv[j], acc[i][j], 0, 0, 0);
    __syncthreads();
  }

#pragma unroll
  for (int i = 0; i < 4; ++i)
#pragma unroll
    for (int j = 0; j < 4; ++j)
#pragma unroll
      for (int q = 0; q < 4; ++q) {
        long gr = row0 + wm + i * 16 + fq * 4 + q;
        long gc = col0 + wn + j * 16 + fr;
        float v = acc[i][j][q];
        if constexpr (EPI == 0) {
          ((u16*)C0)[gr * (long)N + gc] = f2b(v);
        } else if constexpr (EPI == 1) {
          ((u16*)C0)[gr * (long)N + gc] = f2b(tanhf(v + bias[gc]) * pw[gc]);
        } else if constexpr (EPI == 2) {
          if (gr < M) ((float*)C0)[gr * (long)N + gc] = v + bias[gc];
        } else {  // EPI == 3
          if (gr < M) {
            long bb = gr & 31, tt = gr >> 5;
            float o = v + bias[gc];
            __builtin_nontemporal_store(o, &((float*)C0)[(bb * 31 + tt) * (long)N + gc]);
          }
        }
      }
}

// ---------------- persistent recurrence kernel v5 (r6 + surgical phase-A fix) ----------------
// 256 blocks x 512 threads, cooperative. r6's relaxed barrier. Cross-block data
// via UC stores into STEP-UNIQUE buffers + cold plain reads (r8-validated).
//
// Phase A (gates GEMV, replication-free): block owns rows [blk*13,+13) of Wcat
//   (bf16, 26 KB unique/block -> 6.8 MB/step chip-wide, partitioned regardless
//   of XCD mapping). Thread (ab=tid>>4, akc=tid&15): 64 f32 h values in regs
//   from permuted hstage[t] (coalesced float4s), 13 rows x unpack-fma,
//   16-lane shfl reduce, UC store to gstage[t][b][r].
// Phase B: EXACTLY r6 (b=blk>>3, jc=blk&7, bf16 wvfb/FWb, hl2-in-LDS GRU),
//   except gates read plain from gstage[t] and h written UC to hstage[t+1]
//   (permuted layout).
__global__ __launch_bounds__(512)
void persist(const u16* __restrict__ WcatB, const float* __restrict__ bcat,
             const u16* __restrict__ wvfb, const u16* __restrict__ FWb,
             const float* __restrict__ GX, const float* __restrict__ pbv,
             const float* __restrict__ h0,
             float* __restrict__ hstage,   // 32 x (32*1024) f32, permuted
             float* __restrict__ gstage,   // 31 x (32*3328) f32
             u16* __restrict__ Hbuf, unsigned* __restrict__ cnt) {
  const int tid = threadIdx.x;
  const int blk = blockIdx.x;
  const int ab = tid >> 4, akc = tid & 15;  // phase A role
  const int r0 = blk * 13;
  const int b = blk >> 3, jc = blk & 7;     // phase B role

  __shared__ float uhl[256];
  __shared__ float part[512];
  __shared__ float attnv[128];
  __shared__ float gmp[3][512];
  __shared__ float hl2[128];                // persistent f32 h slice (b, jc)

  const float pb0 = pbv[0];
  if (tid < 128) hl2[tid] = h0[b * 1024 + jc * 128 + tid];

  auto xbar = [&](unsigned target) {
    __syncthreads();
    if (tid == 0) {
      __hip_atomic_fetch_add(cnt, 1u, __ATOMIC_RELAXED, __HIP_MEMORY_SCOPE_AGENT);
      while (__hip_atomic_load(cnt, __ATOMIC_RELAXED, __HIP_MEMORY_SCOPE_AGENT) < target) {
        __builtin_amdgcn_s_sleep(2);
      }
    }
    __syncthreads();
  };

  for (int t = 0; t < 31; ++t) {
    const float* hs = hstage + (long)t * 32768;
    float* gst = gstage + (long)t * 106496;

    // ===== phase A: replication-free gates GEMV =====
    {
      float hf[64];
      // permuted layout: coalesced across akc lanes
#pragma unroll
      for (int j = 0; j < 16; ++j) {
        float4 v = *(const float4*)(hs + ab * 1024 + j * 64 + akc * 4);
        hf[4 * j] = v.x; hf[4 * j + 1] = v.y; hf[4 * j + 2] = v.z; hf[4 * j + 3] = v.w;
      }
      // hf[4j+e] corresponds to m = akc*64 + 4j + e?  No: permuted idx(b,m)
      // stores m at (j=(m&63)>>2, akc=m>>6, e=m&3). So this thread (akc) holds
      // m = akc... inverse: element (j,e) here is m with (m&63)>>2 == j,
      // m>>6 == akc, m&3 == e  ->  m = akc*64 ... wait: m>>6==akc gives
      // m in [akc*64, akc*64+64), (m&63)>>2==j, m&3==e -> m = akc*64+j*4+e.
      // So hf[4j+e] = h[b=ab][akc*64 + 4j + e]: a contiguous 64-chunk. Matches
      // weight slice [akc*64, +64) below.
#pragma unroll
      for (int rr = 0; rr < 13; ++rr) {
        const u16* wr = WcatB + (long)(r0 + rr) * 1024 + akc * 64;
        float p = 0.f;
#pragma unroll
        for (int j = 0; j < 8; ++j) {
          short8 wv = *(const short8*)(wr + j * 8);
#pragma unroll
          for (int e = 0; e < 8; ++e) p += b2f((u16)wv[e]) * hf[j * 8 + e];
        }
        p += __shfl_xor(p, 1);
        p += __shfl_xor(p, 2);
        p += __shfl_xor(p, 4);
        p += __shfl_xor(p, 8);
        if (akc == 0) astf(gst + (long)ab * 3328 + r0 + rr, p);
      }
    }
    xbar(256u * (2 * t + 1));

    // ===== phase B: attention + GRU (r6 structure) =====
    if (tid < 256) uhl[tid] = tanhf(gst[(long)b * 3328 + tid] + bcat[tid]);
    __syncthreads();
    {
      const int s = tid & 127, q = tid >> 7;
      const u16* wr = wvfb + ((long)(b * 128 + s)) * 256 + q * 64;
      const float* uq = &uhl[q * 64];
      float p = 0.f;
#pragma unroll
      for (int d = 0; d < 64; d += 8) {
        short8 wv = *(const short8*)(wr + d);
#pragma unroll
        for (int e = 0; e < 8; ++e) p += b2f((u16)wv[e]) * uq[d + e];
      }
      part[tid] = p;
    }
    __syncthreads();
    if (tid < 128)
      attnv[tid] = part[tid] + part[tid + 128] + part[tid + 256] + part[tid + 384] + pb0;
    __syncthreads();
    if (tid < 64) {
      float m = fmaxf(attnv[tid], attnv[tid + 64]);
#pragma unroll
      for (int o = 32; o; o >>= 1) m = fmaxf(m, __shfl_xor(m, o));
      float e0 = expf(attnv[tid] - m), e1 = expf(attnv[tid + 64] - m);
      float s2 = e0 + e1;
#pragma unroll
      for (int o = 32; o; o >>= 1) s2 += __shfl_xor(s2, o);
      float inv = 1.f / s2;
      attnv[tid] = e0 * inv;
      attnv[tid + 64] = e1 * inv;
    }
    __syncthreads();
    {
      const int ml = tid & 127, sh = tid >> 7;
      const int col = jc * 128 + ml;
      float g0 = 0.f, g1 = 0.f, g2 = 0.f;
      const u16* fw = FWb + ((long)(b * 128 + sh * 32)) * 3072 + col;
#pragma unroll 4
      for (int s = 0; s < 32; ++s) {
        float a = attnv[sh * 32 + s];
        g0 += a * b2f(fw[0]);
        g1 += a * b2f(fw[1024]);
        g2 += a * b2f(fw[2048]);
        fw += 3072;
      }
      gmp[0][tid] = g0; gmp[1][tid] = g1; gmp[2][tid] = g2;
    }
    __syncthreads();
    if (tid < 128) {
      const int m = jc * 128 + tid;
      float gm0 = gmp[0][tid] + gmp[0][tid + 128] + gmp[0][tid + 256] + gmp[0][tid + 384];
      float gm1 = gmp[1][tid] + gmp[1][tid + 128] + gmp[1][tid + 256] + gmp[1][tid + 384];
      float gm2 = gmp[2][tid] + gmp[2][tid + 128] + gmp[2][tid + 256] + gmp[2][tid + 384];
      float gh0 = gst[(long)b * 3328 + 256 + m] + bcat[256 + m];
      float gh1 = gst[(long)b * 3328 + 1280 + m] + bcat[1280 + m];
      float gh2 = gst[(long)b * 3328 + 2304 + m] + bcat[2304 + m];
      const long gxo = ((long)t * 32 + b) * 3072;
      float xr = GX[gxo + m] + gm0;
      float xz = GX[gxo + 1024 + m] + gm1;
      float xn = GX[gxo + 2048 + m] + gm2;
      float r = 1.f / (1.f + expf(-(xr + gh0)));
      float z = 1.f / (1.f + expf(-(xz + gh1)));
      float n = tanhf(xn + r * gh2);
      float h2 = (1.f - z) * n + z * hl2[tid];
      hl2[tid] = h2;
      Hbuf[((long)t * 32 + b) * 1024 + m] = f2b(h2);
      // permuted hstage[t+1] UC store
      astf(hstage + (long)(t + 1) * 32768 + b * 1024 +
               ((m & 63) >> 2) * 64 + (m >> 6) * 4 + (m & 3),
           h2);
    }
    xbar(256u * (2 * t + 2));
  }
}

// ---------------- launcher ----------------

extern "C" void kernel_launch(void* const* d_in, const int* in_sizes, int n_in,
                              void* d_out, int out_size, void* d_ws, size_t ws_size,
                              hipStream_t stream) {
  const float* f    = (const float*)d_in[0];
  const float* h0   = (const float*)d_in[1];
  const float* gt   = (const float*)d_in[2];
  const float* U_w  = (const float*)d_in[4];
  const float* U_b  = (const float*)d_in[5];
  const float* V_w  = (const float*)d_in[6];
  const float* V_b  = (const float*)d_in[7];
  const float* P_w  = (const float*)d_in[8];
  const float* P_b  = (const float*)d_in[9];
  const float* W_ih = (const float*)d_in[10];
  const float* b_ih = (const float*)d_in[11];
  const float* W_hh = (const float*)d_in[12];
  const float* b_hh = (const float*)d_in[13];
  const float* dw   = (const float*)d_in[14];
  const float* db   = (const float*)d_in[15];

  char* w = (char*)d_ws;
  auto alloc = [&](size_t bytes) { char* p = w; w += (bytes + 255) & ~255ULL; return p; };

  u16*      fbf    = (u16*)alloc(4096L * 1024 * 2);
  u16*      VwB    = (u16*)alloc(256L * 1024 * 2);
  u16*      WcatB  = (u16*)alloc(3328L * 1024 * 2);   // bf16 [U_w; W_hh]
  u16*      WxB    = (u16*)alloc(3072L * 512 * 2);
  u16*      WmB    = (u16*)alloc(3072L * 1024 * 2);
  u16*      dwB    = (u16*)alloc(32000L * 1024 * 2);
  u16*      Xb     = (u16*)alloc(1024L * 512 * 2);
  u16*      wvfb   = (u16*)alloc(4096L * 256 * 2);
  float*    GX     = (float*)alloc(1024L * 3072 * 4);
  u16*      FWb    = (u16*)alloc(4096L * 3072 * 2);
  float*    hstage = (float*)alloc(32L * 32768 * 4);   // step-unique permuted h
  float*    gstage = (float*)alloc(31L * 106496 * 4);  // step-unique gates
  u16*      Hbuf   = (u16*)alloc(1024L * 1024 * 2);
  float*    bcat   = (float*)alloc(3328L * 4);
  unsigned* cnt    = (unsigned*)alloc(256);

  auto cvg = [](long n) { long g = (n + 1023) / 1024; return (int)(g > 2048 ? 2048 : g); };

  cvt_flat<<<cvg(4194304), 256, 0, stream>>>(f, fbf, 4194304);
  cvt_flat<<<cvg(262144), 256, 0, stream>>>(V_w, VwB, 262144);
  cvt_flat<<<cvg(262144), 256, 0, stream>>>(U_w, WcatB, 262144);
  cvt_flat<<<cvg(3145728), 256, 0, stream>>>(W_hh, WcatB + 262144L, 3145728);
  cvt_strided<<<2048, 256, 0, stream>>>(W_ih, WxB, 3072L * 512, 9, 1536, 0);
  cvt_strided<<<2048, 256, 0, stream>>>(W_ih, WmB, 3072L * 1024, 10, 1536, 512);
  cvt_flat<<<cvg(32768000), 256, 0, stream>>>(dw, dwB, 32768000);
  cvt_x<<<2048, 256, 0, stream>>>(gt, Xb);
  cvt_hperm<<<128, 256, 0, stream>>>(h0, hstage);
  hipMemcpyAsync(bcat, U_b, 256 * 4, hipMemcpyDeviceToDevice, stream);
  hipMemcpyAsync(bcat + 256, b_hh, 3072 * 4, hipMemcpyDeviceToDevice, stream);
  hipMemsetAsync(cnt, 0, 4, stream);

  // loop-invariant GEMMs (bf16)
  gemm_bt<1><<<dim3(2, 32), 256, 0, stream>>>(fbf, VwB, wvfb, V_b, P_w, 4096, 256, 1024);
  gemm_bt<2><<<dim3(24, 8), 256, 0, stream>>>(Xb, WxB, GX, b_ih, nullptr, 992, 3072, 512);
  gemm_bt<0><<<dim3(24, 32), 256, 0, stream>>>(fbf, WmB, FWb, nullptr, nullptr, 4096, 3072, 1024);

  // full recurrence: persistent kernel (r6 + replication-free phase A)
  {
    void* ka[] = {(void*)&WcatB, (void*)&bcat,   (void*)&wvfb, (void*)&FWb,
                  (void*)&GX,    (void*)&P_b,    (void*)&h0,   (void*)&hstage,
                  (void*)&gstage, (void*)&Hbuf,  (void*)&cnt};
    hipLaunchCooperativeKernel((void*)persist, dim3(256), dim3(512), ka, 0, stream);
  }

  // logits
  gemm_bt<3><<<dim3(250, 8), 256, 0, stream>>>(Hbuf, dwB, (float*)d_out, db, nullptr,
                                               992, 32000, 1024);
}

// Round 11
// 2100.461 us; speedup vs baseline: 5.3597x; 5.3597x over previous
//
#include <hip/hip_runtime.h>
#include <hip/hip_bf16.h>
#include <math.h>

typedef unsigned short u16;
typedef unsigned long long u64;
typedef __attribute__((ext_vector_type(8))) short short8;
typedef __attribute__((ext_vector_type(4))) float f32x4;

static __device__ __forceinline__ u16 f2b(float x) {
  __hip_bfloat16 h = __float2bfloat16(x);
  return *reinterpret_cast<u16*>(&h);
}
static __device__ __forceinline__ float b2f(u16 u) {
  unsigned int v = ((unsigned int)u) << 16;
  float f;
  __builtin_memcpy(&f, &v, 4);
  return f;
}

// agent-scope relaxed (cache-bypassing) accessors
static __device__ __forceinline__ float aldf(const float* p) {
  return __hip_atomic_load(const_cast<float*>(p), __ATOMIC_RELAXED, __HIP_MEMORY_SCOPE_AGENT);
}
static __device__ __forceinline__ void astf(float* p, float v) {
  __hip_atomic_store(p, v, __ATOMIC_RELAXED, __HIP_MEMORY_SCOPE_AGENT);
}
static __device__ __forceinline__ u64 ald8(const u64* p) {
  return __hip_atomic_load(const_cast<u64*>(p), __ATOMIC_RELAXED, __HIP_MEMORY_SCOPE_AGENT);
}

// ---------------- conversion kernels ----------------

__global__ void cvt_flat(const float* __restrict__ s, u16* __restrict__ d, long n) {
  long i = ((long)blockIdx.x * 256 + threadIdx.x) * 4;
  long stride = (long)gridDim.x * 1024;
  for (; i < n; i += stride) {
    float4 v = *(const float4*)(s + i);
    ushort4 o;
    o.x = f2b(v.x); o.y = f2b(v.y); o.z = f2b(v.z); o.w = f2b(v.w);
    *(ushort4*)(d + i) = o;
  }
}

__global__ void cvt_strided(const float* __restrict__ s, u16* __restrict__ d,
                            long total, int lshift, long sstride, long soff) {
  long i = (long)blockIdx.x * 256 + threadIdx.x;
  long step = (long)gridDim.x * 256;
  long mask = (1L << lshift) - 1;
  for (; i < total; i += step) {
    long r = i >> lshift;
    long c = i & mask;
    d[i] = f2b(s[r * sstride + soff + c]);
  }
}

__global__ void cvt_x(const float* __restrict__ gt, u16* __restrict__ d) {
  long idx = (long)blockIdx.x * 256 + threadIdx.x;
  if (idx >= 1024L * 512) return;
  long m = idx >> 9;
  int k = (int)(idx & 511);
  if (m < 992) {
    int tt = (int)(m >> 5), b = (int)(m & 31);
    d[idx] = f2b(gt[((long)b * 32 + tt) * 512 + k]);
  } else {
    d[idx] = 0;
  }
}

// ---------------- generic MFMA GEMM: C = A(M,K) * B(N,K)^T ----------------
template<int EPI>
__global__ __launch_bounds__(256)
void gemm_bt(const u16* __restrict__ A, const u16* __restrict__ B,
             void* __restrict__ C0,
             const float* __restrict__ bias, const float* __restrict__ pw,
             int M, int N, int K) {
  __shared__ u16 As[4096];
  __shared__ u16 Bs[4096];
  const int tid = threadIdx.x;
  const int lane = tid & 63, wid = tid >> 6;

  int gx = gridDim.x, gy = gridDim.y;
  int orig = blockIdx.y * gx + blockIdx.x;
  int G = gx < 8 ? gx : 8;
  int ng = gx / G;
  int full = ng * G * gy;
  int ct, rt;
  if (orig < full) {
    int grp = orig / (G * gy), rem = orig % (G * gy);
    ct = grp * G + rem % G;
    rt = rem / G;
  } else {
    int Gt = gx - ng * G;
    int rem = orig - full;
    ct = ng * G + rem % Gt;
    rt = rem / Gt;
  }
  const long row0 = (long)rt * 128;
  const long col0 = (long)ct * 128;

  const int wm = (wid >> 1) * 64, wn = (wid & 1) * 64;
  const int fr = lane & 15, fq = lane >> 4;
  const int sr = wid * 16 + (lane >> 2);
  const int sc = (lane & 3) * 8;

  const u16* Ag0 = A + (row0 + sr) * (long)K + sc;
  const u16* Ag1 = Ag0 + 64 * (long)K;
  const u16* Bg0 = B + (col0 + sr) * (long)K + sc;
  const u16* Bg1 = Bg0 + 64 * (long)K;

  u16* AsW0 = &As[wid * 512];
  u16* AsW1 = &As[2048 + wid * 512];
  u16* BsW0 = &Bs[wid * 512];
  u16* BsW1 = &Bs[2048 + wid * 512];

  f32x4 acc[4][4];
#pragma unroll
  for (int i = 0; i < 4; ++i)
#pragma unroll
    for (int j = 0; j < 4; ++j) acc[i][j] = {0.f, 0.f, 0.f, 0.f};

  for (int k0 = 0; k0 < K; k0 += 32) {
    __builtin_amdgcn_global_load_lds((const __attribute__((address_space(1))) void*)(Ag0 + k0),
                                     (__attribute__((address_space(3))) void*)AsW0, 16, 0, 0);
    __builtin_amdgcn_global_load_lds((const __attribute__((address_space(1))) void*)(Ag1 + k0),
                                     (__attribute__((address_space(3))) void*)AsW1, 16, 0, 0);
    __builtin_amdgcn_global_load_lds((const __attribute__((address_space(1))) void*)(Bg0 + k0),
                                     (__attribute__((address_space(3))) void*)BsW0, 16, 0, 0);
    __builtin_amdgcn_global_load_lds((const __attribute__((address_space(1))) void*)(Bg1 + k0),
                                     (__attribute__((address_space(3))) void*)BsW1, 16, 0, 0);
    __syncthreads();
    short8 af[4], bfv[4];
#pragma unroll
    for (int i = 0; i < 4; ++i) af[i] = *(const short8*)&As[(wm + i * 16 + fr) * 32 + fq * 8];
#pragma unroll
    for (int i = 0; i < 4; ++i) bfv[i] = *(const short8*)&Bs[(wn + i * 16 + fr) * 32 + fq * 8];
#pragma unroll
    for (int i = 0; i < 4; ++i)
#pragma unroll
      for (int j = 0; j < 4; ++j)
        acc[i][j] = __builtin_amdgcn_mfma_f32_16x16x32_bf16(af[i], bfv[j], acc[i][j], 0, 0, 0);
    __syncthreads();
  }

#pragma unroll
  for (int i = 0; i < 4; ++i)
#pragma unroll
    for (int j = 0; j < 4; ++j)
#pragma unroll
      for (int q = 0; q < 4; ++q) {
        long gr = row0 + wm + i * 16 + fq * 4 + q;
        long gc = col0 + wn + j * 16 + fr;
        float v = acc[i][j][q];
        if constexpr (EPI == 0) {
          ((u16*)C0)[gr * (long)N + gc] = f2b(v);
        } else if constexpr (EPI == 1) {
          ((u16*)C0)[gr * (long)N + gc] = f2b(tanhf(v + bias[gc]) * pw[gc]);
        } else if constexpr (EPI == 2) {
          if (gr < M) ((float*)C0)[gr * (long)N + gc] = v + bias[gc];
        } else {  // EPI == 3
          if (gr < M) {
            long bb = gr & 31, tt = gr >> 5;
            float o = v + bias[gc];
            __builtin_nontemporal_store(o, &((float*)C0)[(bb * 31 + tt) * (long)N + gc]);
          }
        }
      }
}

// ---------------- persistent recurrence kernel (r6 structure, bf16 Wcat) ----------------
// 256 blocks x 512 threads, cooperative. Custom relaxed barrier (r6-proven).
// IDENTICAL to the round-6 kernel (1586 us total, best measured) except Wcat
// is bf16 instead of f32: phase A weight traffic 53 -> 26.5 MB/step. Single-
// variable experiment.
//
// Per step:
//  phase A (gates GEMV): block = (rowg = blk>>2, bg = blk&3). Reads h[8 b's]
//    via UC -> LDS; Wcat bf16 rows [rowg*52,+52) plain cached; writes raw gate
//    dots to gates[b][r] via UC.
//  barrier
//  phase B (attention + GRU): block = (b = blk>>3, jc = blk&7). uh from UC
//    gates + U_b; scores vs wvfb (plain); softmax; gm over FWb jc-slice
//    (plain); gh from UC gates + b_hh; GRU with h-slice persistent in LDS;
//    write h via UC, Hbuf plain.
//  barrier
__global__ __launch_bounds__(512)
void persist(const u16* __restrict__ WcatB, const float* __restrict__ bcat,
             const u16* __restrict__ wvfb, const u16* __restrict__ FWb,
             const float* __restrict__ GX, const float* __restrict__ pbv,
             float* __restrict__ hG, float* __restrict__ gates,
             u16* __restrict__ Hbuf, unsigned* __restrict__ cnt) {
  const int tid = threadIdx.x;
  const int blk = blockIdx.x;
  const int rowg = blk >> 2, bg = blk & 3;  // phase A role
  const int b = blk >> 3, jc = blk & 7;     // phase B role

  __shared__ float hA[8][1032];   // padded stride: bank-conflict-free
  __shared__ float uhl[256];
  __shared__ float part[512];
  __shared__ float attnv[128];
  __shared__ float gmp[3][512];
  __shared__ float hl2[128];      // this block's persistent h slice

  const float pb0 = pbv[0];

  if (tid < 128) hl2[tid] = hG[(long)b * 1024 + jc * 128 + tid];

  auto xbar = [&](unsigned target) {
    __syncthreads();
    if (tid == 0) {
      __hip_atomic_fetch_add(cnt, 1u, __ATOMIC_RELAXED, __HIP_MEMORY_SCOPE_AGENT);
      while (__hip_atomic_load(cnt, __ATOMIC_RELAXED, __HIP_MEMORY_SCOPE_AGENT) < target) {
        __builtin_amdgcn_s_sleep(2);
      }
    }
    __syncthreads();
  };

  for (int t = 0; t < 31; ++t) {
    // ---------------- phase A: gate dots, batched over 8 b ----------------
    for (int i = tid; i < 4096; i += 512) {
      int bi = i >> 9, off = (i & 511) << 1;
      u64 v = ald8((const u64*)(hG + (long)(bg * 8 + bi) * 1024 + off));
      float2 f2v;
      __builtin_memcpy(&f2v, &v, 8);
      hA[bi][off] = f2v.x;
      hA[bi][off + 1] = f2v.y;
    }
    __syncthreads();
    if (tid < 416) {
      const int bi = tid & 7, ri = tid >> 3;
      const int r = rowg * 52 + ri;
      const u16* wr = WcatB + (long)r * 1024;
      const float* hh = hA[bi];
      float acc = 0.f;
#pragma unroll 8
      for (int k = 0; k < 1024; k += 8) {
        short8 wv = *(const short8*)(wr + k);
#pragma unroll
        for (int e = 0; e < 8; ++e) acc += b2f((u16)wv[e]) * hh[k + e];
      }
      astf(gates + (long)(bg * 8 + bi) * 3328 + r, acc);
    }
    xbar(256u * (2 * t + 1));

    // ---------------- phase B: attention + GRU ----------------
    if (tid < 128) {
      u64 v = ald8((const u64*)(gates + (long)b * 3328 + tid * 2));
      float2 f2v;
      __builtin_memcpy(&f2v, &v, 8);
      uhl[tid * 2] = tanhf(f2v.x + bcat[tid * 2]);
      uhl[tid * 2 + 1] = tanhf(f2v.y + bcat[tid * 2 + 1]);
    }
    __syncthreads();
    {
      const int s = tid & 127, q = tid >> 7;
      const u16* wr = wvfb + ((long)(b * 128 + s)) * 256 + q * 64;
      const float* uq = &uhl[q * 64];
      float p = 0.f;
#pragma unroll
      for (int d = 0; d < 64; d += 8) {
        short8 wv = *(const short8*)(wr + d);
#pragma unroll
        for (int e = 0; e < 8; ++e) p += b2f((u16)wv[e]) * uq[d + e];
      }
      part[tid] = p;
    }
    __syncthreads();
    if (tid < 128)
      attnv[tid] = part[tid] + part[tid + 128] + part[tid + 256] + part[tid + 384] + pb0;
    __syncthreads();
    if (tid < 64) {
      float m = fmaxf(attnv[tid], attnv[tid + 64]);
#pragma unroll
      for (int o = 32; o; o >>= 1) m = fmaxf(m, __shfl_xor(m, o));
      float e0 = expf(attnv[tid] - m), e1 = expf(attnv[tid + 64] - m);
      float s2 = e0 + e1;
#pragma unroll
      for (int o = 32; o; o >>= 1) s2 += __shfl_xor(s2, o);
      float inv = 1.f / s2;
      attnv[tid] = e0 * inv;
      attnv[tid + 64] = e1 * inv;
    }
    __syncthreads();
    {
      const int ml = tid & 127, sh = tid >> 7;
      const int col = jc * 128 + ml;
      float g0 = 0.f, g1 = 0.f, g2 = 0.f;
      const u16* fw = FWb + ((long)(b * 128 + sh * 32)) * 3072 + col;
#pragma unroll 4
      for (int s = 0; s < 32; ++s) {
        float a = attnv[sh * 32 + s];
        g0 += a * b2f(fw[0]);
        g1 += a * b2f(fw[1024]);
        g2 += a * b2f(fw[2048]);
        fw += 3072;
      }
      gmp[0][tid] = g0; gmp[1][tid] = g1; gmp[2][tid] = g2;
    }
    __syncthreads();
    if (tid < 128) {
      const int m = jc * 128 + tid;
      float gm0 = gmp[0][tid] + gmp[0][tid + 128] + gmp[0][tid + 256] + gmp[0][tid + 384];
      float gm1 = gmp[1][tid] + gmp[1][tid + 128] + gmp[1][tid + 256] + gmp[1][tid + 384];
      float gm2 = gmp[2][tid] + gmp[2][tid + 128] + gmp[2][tid + 256] + gmp[2][tid + 384];
      float gh0 = aldf(gates + (long)b * 3328 + 256 + m) + bcat[256 + m];
      float gh1 = aldf(gates + (long)b * 3328 + 1280 + m) + bcat[1280 + m];
      float gh2 = aldf(gates + (long)b * 3328 + 2304 + m) + bcat[2304 + m];
      const long gxo = ((long)t * 32 + b) * 3072;
      float xr = GX[gxo + m] + gm0;
      float xz = GX[gxo + 1024 + m] + gm1;
      float xn = GX[gxo + 2048 + m] + gm2;
      float r = 1.f / (1.f + expf(-(xr + gh0)));
      float z = 1.f / (1.f + expf(-(xz + gh1)));
      float n = tanhf(xn + r * gh2);
      float h2 = (1.f - z) * n + z * hl2[tid];
      hl2[tid] = h2;
      astf(hG + (long)b * 1024 + m, h2);
      Hbuf[((long)t * 32 + b) * 1024 + m] = f2b(h2);
    }
    xbar(256u * (2 * t + 2));
  }
}

// ---------------- launcher ----------------

extern "C" void kernel_launch(void* const* d_in, const int* in_sizes, int n_in,
                              void* d_out, int out_size, void* d_ws, size_t ws_size,
                              hipStream_t stream) {
  const float* f    = (const float*)d_in[0];
  const float* h0   = (const float*)d_in[1];
  const float* gt   = (const float*)d_in[2];
  const float* U_w  = (const float*)d_in[4];
  const float* U_b  = (const float*)d_in[5];
  const float* V_w  = (const float*)d_in[6];
  const float* V_b  = (const float*)d_in[7];
  const float* P_w  = (const float*)d_in[8];
  const float* P_b  = (const float*)d_in[9];
  const float* W_ih = (const float*)d_in[10];
  const float* b_ih = (const float*)d_in[11];
  const float* W_hh = (const float*)d_in[12];
  const float* b_hh = (const float*)d_in[13];
  const float* dw   = (const float*)d_in[14];
  const float* db   = (const float*)d_in[15];

  char* w = (char*)d_ws;
  auto alloc = [&](size_t bytes) { char* p = w; w += (bytes + 255) & ~255ULL; return p; };

  u16*      fbf   = (u16*)alloc(4096L * 1024 * 2);
  u16*      VwB   = (u16*)alloc(256L * 1024 * 2);
  u16*      WcatB = (u16*)alloc(3328L * 1024 * 2);  // bf16 [U_w; W_hh]
  u16*      WxB   = (u16*)alloc(3072L * 512 * 2);
  u16*      WmB   = (u16*)alloc(3072L * 1024 * 2);
  u16*      dwB   = (u16*)alloc(32000L * 1024 * 2);
  u16*      Xb    = (u16*)alloc(1024L * 512 * 2);
  u16*      wvfb  = (u16*)alloc(4096L * 256 * 2);
  float*    GX    = (float*)alloc(1024L * 3072 * 4);
  u16*      FWb   = (u16*)alloc(4096L * 3072 * 2);
  float*    hG    = (float*)alloc(32L * 1024 * 4);
  float*    gates = (float*)alloc(32L * 3328 * 4);
  u16*      Hbuf  = (u16*)alloc(1024L * 1024 * 2);
  float*    bcat  = (float*)alloc(3328L * 4);
  unsigned* cnt   = (unsigned*)alloc(256);

  auto cvg = [](long n) { long g = (n + 1023) / 1024; return (int)(g > 2048 ? 2048 : g); };

  cvt_flat<<<cvg(4194304), 256, 0, stream>>>(f, fbf, 4194304);
  cvt_flat<<<cvg(262144), 256, 0, stream>>>(V_w, VwB, 262144);
  cvt_flat<<<cvg(262144), 256, 0, stream>>>(U_w, WcatB, 262144);
  cvt_flat<<<cvg(3145728), 256, 0, stream>>>(W_hh, WcatB + 262144L, 3145728);
  cvt_strided<<<2048, 256, 0, stream>>>(W_ih, WxB, 3072L * 512, 9, 1536, 0);
  cvt_strided<<<2048, 256, 0, stream>>>(W_ih, WmB, 3072L * 1024, 10, 1536, 512);
  cvt_flat<<<cvg(32768000), 256, 0, stream>>>(dw, dwB, 32768000);
  cvt_x<<<2048, 256, 0, stream>>>(gt, Xb);
  hipMemcpyAsync(hG, h0, 32L * 1024 * 4, hipMemcpyDeviceToDevice, stream);
  hipMemcpyAsync(bcat, U_b, 256 * 4, hipMemcpyDeviceToDevice, stream);
  hipMemcpyAsync(bcat + 256, b_hh, 3072 * 4, hipMemcpyDeviceToDevice, stream);
  hipMemsetAsync(cnt, 0, 4, stream);

  // loop-invariant GEMMs (bf16)
  gemm_bt<1><<<dim3(2, 32), 256, 0, stream>>>(fbf, VwB, wvfb, V_b, P_w, 4096, 256, 1024);
  gemm_bt<2><<<dim3(24, 8), 256, 0, stream>>>(Xb, WxB, GX, b_ih, nullptr, 992, 3072, 512);
  gemm_bt<0><<<dim3(24, 32), 256, 0, stream>>>(fbf, WmB, FWb, nullptr, nullptr, 4096, 3072, 1024);

  // full recurrence: one persistent kernel, custom non-invalidating barrier
  {
    void* ka[] = {(void*)&WcatB, (void*)&bcat, (void*)&wvfb, (void*)&FWb,
                  (void*)&GX,    (void*)&P_b,  (void*)&hG,   (void*)&gates,
                  (void*)&Hbuf,  (void*)&cnt};
    hipLaunchCooperativeKernel((void*)persist, dim3(256), dim3(512), ka, 0, stream);
  }

  // logits
  gemm_bt<3><<<dim3(250, 8), 256, 0, stream>>>(Hbuf, dwB, (float*)d_out, db, nullptr,
                                               992, 32000, 1024);
}

// Round 12
// 1497.972 us; speedup vs baseline: 7.5153x; 1.4022x over previous
//
#include <hip/hip_runtime.h>
#include <hip/hip_bf16.h>
#include <math.h>

typedef unsigned short u16;
typedef unsigned long long u64;
typedef __attribute__((ext_vector_type(8))) short short8;
typedef __attribute__((ext_vector_type(4))) float f32x4;

static __device__ __forceinline__ u16 f2b(float x) {
  __hip_bfloat16 h = __float2bfloat16(x);
  return *reinterpret_cast<u16*>(&h);
}
static __device__ __forceinline__ float b2f(u16 u) {
  unsigned int v = ((unsigned int)u) << 16;
  float f;
  __builtin_memcpy(&f, &v, 4);
  return f;
}

// agent-scope relaxed (cache-bypassing) accessors
static __device__ __forceinline__ float aldf(const float* p) {
  return __hip_atomic_load(const_cast<float*>(p), __ATOMIC_RELAXED, __HIP_MEMORY_SCOPE_AGENT);
}
static __device__ __forceinline__ void astf(float* p, float v) {
  __hip_atomic_store(p, v, __ATOMIC_RELAXED, __HIP_MEMORY_SCOPE_AGENT);
}
static __device__ __forceinline__ u64 ald8(const u64* p) {
  return __hip_atomic_load(const_cast<u64*>(p), __ATOMIC_RELAXED, __HIP_MEMORY_SCOPE_AGENT);
}

// ---------------- conversion kernels ----------------

__global__ void cvt_flat(const float* __restrict__ s, u16* __restrict__ d, long n) {
  long i = ((long)blockIdx.x * 256 + threadIdx.x) * 4;
  long stride = (long)gridDim.x * 1024;
  for (; i < n; i += stride) {
    float4 v = *(const float4*)(s + i);
    ushort4 o;
    o.x = f2b(v.x); o.y = f2b(v.y); o.z = f2b(v.z); o.w = f2b(v.w);
    *(ushort4*)(d + i) = o;
  }
}

__global__ void cvt_strided(const float* __restrict__ s, u16* __restrict__ d,
                            long total, int lshift, long sstride, long soff) {
  long i = (long)blockIdx.x * 256 + threadIdx.x;
  long step = (long)gridDim.x * 256;
  long mask = (1L << lshift) - 1;
  for (; i < total; i += step) {
    long r = i >> lshift;
    long c = i & mask;
    d[i] = f2b(s[r * sstride + soff + c]);
  }
}

__global__ void cvt_x(const float* __restrict__ gt, u16* __restrict__ d) {
  long idx = (long)blockIdx.x * 256 + threadIdx.x;
  if (idx >= 1024L * 512) return;
  long m = idx >> 9;
  int k = (int)(idx & 511);
  if (m < 992) {
    int tt = (int)(m >> 5), b = (int)(m & 31);
    d[idx] = f2b(gt[((long)b * 32 + tt) * 512 + k]);
  } else {
    d[idx] = 0;
  }
}

// ---------------- generic MFMA GEMM: C = A(M,K) * B(N,K)^T ----------------
template<int EPI>
__global__ __launch_bounds__(256)
void gemm_bt(const u16* __restrict__ A, const u16* __restrict__ B,
             void* __restrict__ C0,
             const float* __restrict__ bias, const float* __restrict__ pw,
             int M, int N, int K) {
  __shared__ u16 As[4096];
  __shared__ u16 Bs[4096];
  const int tid = threadIdx.x;
  const int lane = tid & 63, wid = tid >> 6;

  int gx = gridDim.x, gy = gridDim.y;
  int orig = blockIdx.y * gx + blockIdx.x;
  int G = gx < 8 ? gx : 8;
  int ng = gx / G;
  int full = ng * G * gy;
  int ct, rt;
  if (orig < full) {
    int grp = orig / (G * gy), rem = orig % (G * gy);
    ct = grp * G + rem % G;
    rt = rem / G;
  } else {
    int Gt = gx - ng * G;
    int rem = orig - full;
    ct = ng * G + rem % Gt;
    rt = rem / Gt;
  }
  const long row0 = (long)rt * 128;
  const long col0 = (long)ct * 128;

  const int wm = (wid >> 1) * 64, wn = (wid & 1) * 64;
  const int fr = lane & 15, fq = lane >> 4;
  const int sr = wid * 16 + (lane >> 2);
  const int sc = (lane & 3) * 8;

  const u16* Ag0 = A + (row0 + sr) * (long)K + sc;
  const u16* Ag1 = Ag0 + 64 * (long)K;
  const u16* Bg0 = B + (col0 + sr) * (long)K + sc;
  const u16* Bg1 = Bg0 + 64 * (long)K;

  u16* AsW0 = &As[wid * 512];
  u16* AsW1 = &As[2048 + wid * 512];
  u16* BsW0 = &Bs[wid * 512];
  u16* BsW1 = &Bs[2048 + wid * 512];

  f32x4 acc[4][4];
#pragma unroll
  for (int i = 0; i < 4; ++i)
#pragma unroll
    for (int j = 0; j < 4; ++j) acc[i][j] = {0.f, 0.f, 0.f, 0.f};

  for (int k0 = 0; k0 < K; k0 += 32) {
    __builtin_amdgcn_global_load_lds((const __attribute__((address_space(1))) void*)(Ag0 + k0),
                                     (__attribute__((address_space(3))) void*)AsW0, 16, 0, 0);
    __builtin_amdgcn_global_load_lds((const __attribute__((address_space(1))) void*)(Ag1 + k0),
                                     (__attribute__((address_space(3))) void*)AsW1, 16, 0, 0);
    __builtin_amdgcn_global_load_lds((const __attribute__((address_space(1))) void*)(Bg0 + k0),
                                     (__attribute__((address_space(3))) void*)BsW0, 16, 0, 0);
    __builtin_amdgcn_global_load_lds((const __attribute__((address_space(1))) void*)(Bg1 + k0),
                                     (__attribute__((address_space(3))) void*)BsW1, 16, 0, 0);
    __syncthreads();
    short8 af[4], bfv[4];
#pragma unroll
    for (int i = 0; i < 4; ++i) af[i] = *(const short8*)&As[(wm + i * 16 + fr) * 32 + fq * 8];
#pragma unroll
    for (int i = 0; i < 4; ++i) bfv[i] = *(const short8*)&Bs[(wn + i * 16 + fr) * 32 + fq * 8];
#pragma unroll
    for (int i = 0; i < 4; ++i)
#pragma unroll
      for (int j = 0; j < 4; ++j)
        acc[i][j] = __builtin_amdgcn_mfma_f32_16x16x32_bf16(af[i], bfv[j], acc[i][j], 0, 0, 0);
    __syncthreads();
  }

#pragma unroll
  for (int i = 0; i < 4; ++i)
#pragma unroll
    for (int j = 0; j < 4; ++j)
#pragma unroll
      for (int q = 0; q < 4; ++q) {
        long gr = row0 + wm + i * 16 + fq * 4 + q;
        long gc = col0 + wn + j * 16 + fr;
        float v = acc[i][j][q];
        if constexpr (EPI == 0) {
          ((u16*)C0)[gr * (long)N + gc] = f2b(v);
        } else if constexpr (EPI == 1) {
          ((u16*)C0)[gr * (long)N + gc] = f2b(tanhf(v + bias[gc]) * pw[gc]);
        } else if constexpr (EPI == 2) {
          if (gr < M) ((float*)C0)[gr * (long)N + gc] = v + bias[gc];
        } else {  // EPI == 3
          if (gr < M) {
            long bb = gr & 31, tt = gr >> 5;
            float o = v + bias[gc];
            __builtin_nontemporal_store(o, &((float*)C0)[(bb * 31 + tt) * (long)N + gc]);
          }
        }
      }
}

// ---------------- persistent recurrence kernel (r6 structure, 1024 threads) ----------------
// 256 blocks x 1024 threads (16 waves/CU), cooperative. IDENTICAL algorithm &
// traffic to the round-6 kernel (best measured: persist 1308 us, FETCH 40 MB/
// step) -- the ONLY variable is occupancy: 8 -> 16 waves/CU to double
// memory-level parallelism (all loop variants so far plateau at ~1 TB/s
// effective BW with 8 waves/CU; gemm_bt shows 2.9 TB/s is available).
//
// Phase A: block = (rowg = blk>>2, bg = blk&3); thread (kh=tid&1, bi=(tid>>1)&7,
//   ri=tid>>4, ri<52): row r = rowg*52+ri over K-half kh*512..+512, f32 float4
//   reads (r6-proven conflict-free pattern; hA stride 1036 keeps the new lane
//   layout 2-way max), shfl_xor(1) combines K-halves, UC store gates.
// Phase B: block = (b = blk>>3, jc = blk&7); scores/gm chunks scale 4->8.
__global__ __launch_bounds__(1024)
void persist(const float* __restrict__ WcatF, const float* __restrict__ bcat,
             const u16* __restrict__ wvfb, const u16* __restrict__ FWb,
             const float* __restrict__ GX, const float* __restrict__ pbv,
             float* __restrict__ hG, float* __restrict__ gates,
             u16* __restrict__ Hbuf, unsigned* __restrict__ cnt) {
  const int tid = threadIdx.x;
  const int blk = blockIdx.x;
  const int rowg = blk >> 2, bg = blk & 3;  // phase A role
  const int b = blk >> 3, jc = blk & 7;     // phase B role

  __shared__ float hA[8][1036];   // stride 1036: 8 bi -> 8 distinct bank starts
  __shared__ float uhl[256];
  __shared__ float part[1024];
  __shared__ float attnv[128];
  __shared__ float gmp[3][1024];
  __shared__ float hl2[128];      // this block's persistent h slice

  const float pb0 = pbv[0];

  if (tid < 128) hl2[tid] = hG[(long)b * 1024 + jc * 128 + tid];

  auto xbar = [&](unsigned target) {
    __syncthreads();
    if (tid == 0) {
      __hip_atomic_fetch_add(cnt, 1u, __ATOMIC_RELAXED, __HIP_MEMORY_SCOPE_AGENT);
      while (__hip_atomic_load(cnt, __ATOMIC_RELAXED, __HIP_MEMORY_SCOPE_AGENT) < target) {
        __builtin_amdgcn_s_sleep(2);
      }
    }
    __syncthreads();
  };

  for (int t = 0; t < 31; ++t) {
    // ---------------- phase A: gate dots, batched over 8 b ----------------
    for (int i = tid; i < 4096; i += 1024) {
      int bi = i >> 9, off = (i & 511) << 1;
      u64 v = ald8((const u64*)(hG + (long)(bg * 8 + bi) * 1024 + off));
      float2 f2v;
      __builtin_memcpy(&f2v, &v, 8);
      hA[bi][off] = f2v.x;
      hA[bi][off + 1] = f2v.y;
    }
    __syncthreads();
    {
      const int kh = tid & 1, bi = (tid >> 1) & 7, ri = tid >> 4;
      if (ri < 52) {
        const int r = rowg * 52 + ri;
        const float* wr = WcatF + (long)r * 1024 + kh * 512;
        const float* hh = hA[bi] + kh * 512;
        float acc = 0.f;
#pragma unroll 8
        for (int k = 0; k < 512; k += 4) {
          float4 wv = *(const float4*)(wr + k);
          float4 hv = *(const float4*)(hh + k);
          acc += wv.x * hv.x + wv.y * hv.y + wv.z * hv.z + wv.w * hv.w;
        }
        acc += __shfl_xor(acc, 1);
        if (kh == 0) astf(gates + (long)(bg * 8 + bi) * 3328 + r, acc);
      }
    }
    xbar(256u * (2 * t + 1));

    // ---------------- phase B: attention + GRU ----------------
    if (tid < 128) {
      u64 v = ald8((const u64*)(gates + (long)b * 3328 + tid * 2));
      float2 f2v;
      __builtin_memcpy(&f2v, &v, 8);
      uhl[tid * 2] = tanhf(f2v.x + bcat[tid * 2]);
      uhl[tid * 2 + 1] = tanhf(f2v.y + bcat[tid * 2 + 1]);
    }
    __syncthreads();
    {
      const int s = tid & 127, q = tid >> 7;  // q in 0..7, 32 dims each
      const u16* wr = wvfb + ((long)(b * 128 + s)) * 256 + q * 32;
      const float* uq = &uhl[q * 32];
      float p = 0.f;
#pragma unroll
      for (int d = 0; d < 32; d += 8) {
        short8 wv = *(const short8*)(wr + d);
#pragma unroll
        for (int e = 0; e < 8; ++e) p += b2f((u16)wv[e]) * uq[d + e];
      }
      part[tid] = p;
    }
    __syncthreads();
    if (tid < 128) {
      float s8 = pb0;
#pragma unroll
      for (int j = 0; j < 8; ++j) s8 += part[tid + 128 * j];
      attnv[tid] = s8;
    }
    __syncthreads();
    if (tid < 64) {
      float m = fmaxf(attnv[tid], attnv[tid + 64]);
#pragma unroll
      for (int o = 32; o; o >>= 1) m = fmaxf(m, __shfl_xor(m, o));
      float e0 = expf(attnv[tid] - m), e1 = expf(attnv[tid + 64] - m);
      float s2 = e0 + e1;
#pragma unroll
      for (int o = 32; o; o >>= 1) s2 += __shfl_xor(s2, o);
      float inv = 1.f / s2;
      attnv[tid] = e0 * inv;
      attnv[tid + 64] = e1 * inv;
    }
    __syncthreads();
    {
      const int ml = tid & 127, sh = tid >> 7;  // sh in 0..7, 16 s each
      const int col = jc * 128 + ml;
      float g0 = 0.f, g1 = 0.f, g2 = 0.f;
      const u16* fw = FWb + ((long)(b * 128 + sh * 16)) * 3072 + col;
#pragma unroll 4
      for (int s = 0; s < 16; ++s) {
        float a = attnv[sh * 16 + s];
        g0 += a * b2f(fw[0]);
        g1 += a * b2f(fw[1024]);
        g2 += a * b2f(fw[2048]);
        fw += 3072;
      }
      gmp[0][tid] = g0; gmp[1][tid] = g1; gmp[2][tid] = g2;
    }
    __syncthreads();
    if (tid < 128) {
      const int m = jc * 128 + tid;
      float gm0 = 0.f, gm1 = 0.f, gm2 = 0.f;
#pragma unroll
      for (int j = 0; j < 8; ++j) {
        gm0 += gmp[0][tid + 128 * j];
        gm1 += gmp[1][tid + 128 * j];
        gm2 += gmp[2][tid + 128 * j];
      }
      float gh0 = aldf(gates + (long)b * 3328 + 256 + m) + bcat[256 + m];
      float gh1 = aldf(gates + (long)b * 3328 + 1280 + m) + bcat[1280 + m];
      float gh2 = aldf(gates + (long)b * 3328 + 2304 + m) + bcat[2304 + m];
      const long gxo = ((long)t * 32 + b) * 3072;
      float xr = GX[gxo + m] + gm0;
      float xz = GX[gxo + 1024 + m] + gm1;
      float xn = GX[gxo + 2048 + m] + gm2;
      float r = 1.f / (1.f + expf(-(xr + gh0)));
      float z = 1.f / (1.f + expf(-(xz + gh1)));
      float n = tanhf(xn + r * gh2);
      float h2 = (1.f - z) * n + z * hl2[tid];
      hl2[tid] = h2;
      astf(hG + (long)b * 1024 + m, h2);
      Hbuf[((long)t * 32 + b) * 1024 + m] = f2b(h2);
    }
    xbar(256u * (2 * t + 2));
  }
}

// ---------------- launcher ----------------

extern "C" void kernel_launch(void* const* d_in, const int* in_sizes, int n_in,
                              void* d_out, int out_size, void* d_ws, size_t ws_size,
                              hipStream_t stream) {
  const float* f    = (const float*)d_in[0];
  const float* h0   = (const float*)d_in[1];
  const float* gt   = (const float*)d_in[2];
  const float* U_w  = (const float*)d_in[4];
  const float* U_b  = (const float*)d_in[5];
  const float* V_w  = (const float*)d_in[6];
  const float* V_b  = (const float*)d_in[7];
  const float* P_w  = (const float*)d_in[8];
  const float* P_b  = (const float*)d_in[9];
  const float* W_ih = (const float*)d_in[10];
  const float* b_ih = (const float*)d_in[11];
  const float* W_hh = (const float*)d_in[12];
  const float* b_hh = (const float*)d_in[13];
  const float* dw   = (const float*)d_in[14];
  const float* db   = (const float*)d_in[15];

  char* w = (char*)d_ws;
  auto alloc = [&](size_t bytes) { char* p = w; w += (bytes + 255) & ~255ULL; return p; };

  u16*      fbf   = (u16*)alloc(4096L * 1024 * 2);
  u16*      VwB   = (u16*)alloc(256L * 1024 * 2);
  float*    WcatF = (float*)alloc(3328L * 1024 * 4);  // f32 [U_w; W_hh]
  u16*      WxB   = (u16*)alloc(3072L * 512 * 2);
  u16*      WmB   = (u16*)alloc(3072L * 1024 * 2);
  u16*      dwB   = (u16*)alloc(32000L * 1024 * 2);
  u16*      Xb    = (u16*)alloc(1024L * 512 * 2);
  u16*      wvfb  = (u16*)alloc(4096L * 256 * 2);
  float*    GX    = (float*)alloc(1024L * 3072 * 4);
  u16*      FWb   = (u16*)alloc(4096L * 3072 * 2);
  float*    hG    = (float*)alloc(32L * 1024 * 4);
  float*    gates = (float*)alloc(32L * 3328 * 4);
  u16*      Hbuf  = (u16*)alloc(1024L * 1024 * 2);
  float*    bcat  = (float*)alloc(3328L * 4);
  unsigned* cnt   = (unsigned*)alloc(256);

  auto cvg = [](long n) { long g = (n + 1023) / 1024; return (int)(g > 2048 ? 2048 : g); };

  cvt_flat<<<cvg(4194304), 256, 0, stream>>>(f, fbf, 4194304);
  cvt_flat<<<cvg(262144), 256, 0, stream>>>(V_w, VwB, 262144);
  cvt_strided<<<2048, 256, 0, stream>>>(W_ih, WxB, 3072L * 512, 9, 1536, 0);
  cvt_strided<<<2048, 256, 0, stream>>>(W_ih, WmB, 3072L * 1024, 10, 1536, 512);
  cvt_flat<<<cvg(32768000), 256, 0, stream>>>(dw, dwB, 32768000);
  cvt_x<<<2048, 256, 0, stream>>>(gt, Xb);
  hipMemcpyAsync(WcatF, U_w, 256L * 1024 * 4, hipMemcpyDeviceToDevice, stream);
  hipMemcpyAsync(WcatF + 262144, W_hh, 3072L * 1024 * 4, hipMemcpyDeviceToDevice, stream);
  hipMemcpyAsync(hG, h0, 32L * 1024 * 4, hipMemcpyDeviceToDevice, stream);
  hipMemcpyAsync(bcat, U_b, 256 * 4, hipMemcpyDeviceToDevice, stream);
  hipMemcpyAsync(bcat + 256, b_hh, 3072 * 4, hipMemcpyDeviceToDevice, stream);
  hipMemsetAsync(cnt, 0, 4, stream);

  // loop-invariant GEMMs (bf16)
  gemm_bt<1><<<dim3(2, 32), 256, 0, stream>>>(fbf, VwB, wvfb, V_b, P_w, 4096, 256, 1024);
  gemm_bt<2><<<dim3(24, 8), 256, 0, stream>>>(Xb, WxB, GX, b_ih, nullptr, 992, 3072, 512);
  gemm_bt<0><<<dim3(24, 32), 256, 0, stream>>>(fbf, WmB, FWb, nullptr, nullptr, 4096, 3072, 1024);

  // full recurrence: persistent kernel, 16 waves/CU (occupancy experiment)
  {
    void* ka[] = {(void*)&WcatF, (void*)&bcat, (void*)&wvfb, (void*)&FWb,
                  (void*)&GX,    (void*)&P_b,  (void*)&hG,   (void*)&gates,
                  (void*)&Hbuf,  (void*)&cnt};
    hipLaunchCooperativeKernel((void*)persist, dim3(256), dim3(1024), ka, 0, stream);
  }

  // logits
  gemm_bt<3><<<dim3(250, 8), 256, 0, stream>>>(Hbuf, dwB, (float*)d_out, db, nullptr,
                                               992, 32000, 1024);
}